// Round 1
// baseline (1017.172 us; speedup 1.0000x reference)
//
#include <hip/hip_runtime.h>

#define BATCH 32
#define HEADS 12
#define PN    784      // patch_num
#define SIDE  785      // (PATCH_NUM + 1)
#define K     24       // VOTE_PERHEAD == select_num
#define GRID  28       // ceil(sqrt(784)); 28*28 == 784
#define PER_LANE 13    // ceil(784/64)

// Kernel 1: per (b,h) top-24 of x[b,h,0,1:], histogram into counts[b][*].
// One wave (64 lanes) per block. Tie-break: smallest index (matches lax.top_k).
__global__ __launch_bounds__(64) void topk_hist_kernel(
        const float* __restrict__ x, int* __restrict__ counts) {
    const int bh   = blockIdx.x;        // 0..383
    const int b    = bh / HEADS;
    const int lane = threadIdx.x;       // 0..63

    // row 0, skipping CLS column: offset (b*HEADS+h)*785*785 + 1, 784 contiguous
    const float* row = x + (long long)bh * (SIDE * SIDE) + 1;

    float v[PER_LANE];
    #pragma unroll
    for (int j = 0; j < PER_LANE; ++j) {
        int p = lane + 64 * j;
        v[j] = (p < PN) ? row[p] : -INFINITY;
    }

    int* cnt = counts + b * PN;

    for (int r = 0; r < K; ++r) {
        // local argmax (strict > + ascending scan keeps smallest index on ties)
        float bv = -INFINITY; int bi = PN;
        #pragma unroll
        for (int j = 0; j < PER_LANE; ++j) {
            int p = lane + 64 * j;
            if (v[j] > bv) { bv = v[j]; bi = p; }
        }
        // wave butterfly reduce: max value, min index on tie (assoc+comm)
        #pragma unroll
        for (int off = 32; off >= 1; off >>= 1) {
            float ov = __shfl_xor(bv, off);
            int   oi = __shfl_xor(bi, off);
            if (ov > bv || (ov == bv && oi < bi)) { bv = ov; bi = oi; }
        }
        // owner lane retires the winner; lane 0 votes
        if ((bi & 63) == lane) v[bi >> 6] = -INFINITY;
        if (lane == 0) atomicAdd(&cnt[bi], 1);
    }
}

// Kernel 2: per batch — 3x3 SAME conv (weights 1/2/4, exact int) on 28x28
// count grid, then stable descending top-24. key = (conv<<10) | (1023-p)
// so integer max == stable argsort(-count) tie-break (smaller p wins ties).
__global__ __launch_bounds__(64) void conv_topk_kernel(
        const int* __restrict__ counts, int* __restrict__ out) {
    const int b    = blockIdx.x;        // 0..31
    const int lane = threadIdx.x;       // 0..63

    __shared__ int cnt[PN];
    const int* cb = counts + b * PN;
    for (int p = lane; p < PN; p += 64) cnt[p] = cb[p];
    __syncthreads();

    int key[PER_LANE];
    #pragma unroll
    for (int j = 0; j < PER_LANE; ++j) {
        int p = lane + 64 * j;
        if (p < PN) {
            int r = p / GRID, c = p % GRID;
            int s = 0;
            #pragma unroll
            for (int dr = -1; dr <= 1; ++dr) {
                #pragma unroll
                for (int dc = -1; dc <= 1; ++dc) {
                    int rr = r + dr, cc = c + dc;
                    if (rr >= 0 && rr < GRID && cc >= 0 && cc < GRID) {
                        int w = (dr == 0 ? 2 : 1) * (dc == 0 ? 2 : 1);
                        s += w * cnt[rr * GRID + cc];
                    }
                }
            }
            key[j] = (s << 10) | (1023 - p);   // conv<=192 -> fits, keys unique
        } else {
            key[j] = -1;
        }
    }

    for (int r = 0; r < K; ++r) {
        int bk = -1;
        #pragma unroll
        for (int j = 0; j < PER_LANE; ++j) if (key[j] > bk) bk = key[j];
        #pragma unroll
        for (int off = 32; off >= 1; off >>= 1) {
            int ok = __shfl_xor(bk, off);
            if (ok > bk) bk = ok;
        }
        int p = 1023 - (bk & 1023);
        if (lane == 0) out[b * K + r] = p + 1;     // +1 per reference
        if ((p & 63) == lane) key[p >> 6] = -1;    // retire winner
    }
}

extern "C" void kernel_launch(void* const* d_in, const int* in_sizes, int n_in,
                              void* d_out, int out_size, void* d_ws, size_t ws_size,
                              hipStream_t stream) {
    const float* x = (const float*)d_in[0];
    // d_in[1] = kernel (hard-wired 1/2/4 weights), d_in[2] = select_num (==24)
    int* counts = (int*)d_ws;                  // BATCH*PN ints = 100,352 B
    int* out    = (int*)d_out;                 // int32 indices, 32*24

    hipMemsetAsync(counts, 0, BATCH * PN * sizeof(int), stream);
    topk_hist_kernel<<<BATCH * HEADS, 64, 0, stream>>>(x, counts);
    conv_topk_kernel<<<BATCH, 64, 0, stream>>>(counts, out);
}